// Round 17
// baseline (199.616 us; speedup 1.0000x reference)
//
#include <hip/hip_runtime.h>
#include <hip/hip_fp16.h>

// Problem constants (B,C,H,W = 2,3,96,96; D=32)
#define BB 2
#define CC 3
#define NN 9216   // 96*96
#define DD 32
#define NSPLIT 8                      // waves per block
#define KSPLIT 2                      // blocks per 32-query group
#define KEYS_PER_WAVE (NN / (KSPLIT * NSPLIT))  // 576
#define CHUNKS (KEYS_PER_WAVE / 64)   // 9
#define NGROUP (BB * NN / 32)         // 576 query groups
#define L2E 1.44269504f

typedef _Float16 half8 __attribute__((ext_vector_type(8)));
typedef _Float16 half4v __attribute__((ext_vector_type(4)));
typedef __fp16 fp16x2 __attribute__((ext_vector_type(2)));
typedef float float4v __attribute__((ext_vector_type(4)));

#define MFMA_K32(a, b, c) __builtin_amdgcn_mfma_f32_16x16x32_f16((a), (b), (c), 0, 0, 0)
#define MFMA_K16(a, b, c) __builtin_amdgcn_mfma_f32_16x16x16f16((a), (b), (c), 0, 0, 0)

// ---------------------------------------------------------------------------
// Fused prep (R15-proven). Blocks [0,288): QK — hi/lo fp16 split, Q
// pre-scaled by log2(e). Blocks [288,324): PROJECTED V — hP[c][n] =
// (ow.vw).x + ow.vb for c in 0..2 plus a zero row 3 (3x3 cw computed
// in-block; exact fold of the output projection into V).
// ---------------------------------------------------------------------------
__global__ __launch_bounds__(256) void prep_kernel(
    const float* __restrict__ img,
    const float* __restrict__ kw, const float* __restrict__ kb,
    const float* __restrict__ qw, const float* __restrict__ qb,
    const float* __restrict__ vw, const float* __restrict__ vb,
    const float* __restrict__ ow,
    _Float16* __restrict__ fH, _Float16* __restrict__ fL,
    _Float16* __restrict__ gH, _Float16* __restrict__ gL,
    _Float16* __restrict__ hP)
{
    __shared__ float cwb[12];
    int bid = blockIdx.x;
    if (bid < 288) {
        int id = bid * 256 + threadIdx.x;          // [0, BB*NN*4)
        int part = id & 3;
        int n = (id >> 2) % NN;
        int b = (id >> 2) / NN;
        const float* xb = img + (size_t)b * CC * NN + n;
        float x0 = xb[0], x1 = xb[NN], x2 = xb[2 * NN];
        half8 fh, fl, gh, gl;
#pragma unroll
        for (int j = 0; j < 8; j++) {
            int d = part * 8 + j;
            float fv = kw[d * 3 + 0] * x0 + kw[d * 3 + 1] * x1 + kw[d * 3 + 2] * x2 + kb[d];
            float gv = (qw[d * 3 + 0] * x0 + qw[d * 3 + 1] * x1 + qw[d * 3 + 2] * x2 + qb[d]) * L2E;
            _Float16 fhi = (_Float16)fv;
            _Float16 ghi = (_Float16)gv;
            fh[j] = fhi; fl[j] = (_Float16)(fv - (float)fhi);
            gh[j] = ghi; gl[j] = (_Float16)(gv - (float)ghi);
        }
        size_t off = ((size_t)b * NN + n) * DD + part * 8;
        *(half8*)(fH + off) = fh;
        *(half8*)(fL + off) = fl;
        *(half8*)(gH + off) = gh;
        *(half8*)(gL + off) = gl;
    } else {
        int t = threadIdx.x;
        if (t < 9) {
            int c = t / 3, k = t % 3;
            float s = 0.f;
#pragma unroll
            for (int d = 0; d < DD; d++) s += ow[c * DD + d] * vw[d * 3 + k];
            cwb[t] = s;
        } else if (t < 12) {
            int c = t - 9;
            float s = 0.f;
#pragma unroll
            for (int d = 0; d < DD; d++) s += ow[c * DD + d] * vb[d];
            cwb[9 + c] = s;
        }
        __syncthreads();
        const int N8 = NN / 8;
        int id = (bid - 288) * 256 + t;            // [0, BB*4*N8) = 9216
        int n8 = id % N8;
        int row = (id / N8) & 3;
        int b = id / (N8 * 4);
        half8 hv = {0, 0, 0, 0, 0, 0, 0, 0};
        if (row < 3) {
            const float* xb = img + (size_t)b * CC * NN + n8 * 8;
            float w0 = cwb[row * 3 + 0], w1 = cwb[row * 3 + 1],
                  w2 = cwb[row * 3 + 2], bv = cwb[9 + row];
#pragma unroll
            for (int j = 0; j < 8; j++)
                hv[j] = (_Float16)(w0 * xb[j] + w1 * xb[NN + j] + w2 * xb[2 * NN + j] + bv);
        }
        *(half8*)(hP + ((size_t)(b * 4 + row)) * NN + n8 * 8) = hv;
    }
}

// ---------------------------------------------------------------------------
// Flash attention PARTIAL, cross-block split-K x2, FULLY REGISTER inner loop:
//   S (K=32): A = K, B = Q => C[row=n=quad*4+r, col=m=l16]  (R12-proven).
//   P = exp2(s - mnew) packed to fp16 pairs — the score-register C-layout IS
//   the K=16 MFMA B-operand layout (k=quad*4+j, col=l16; HW-verified in R7).
//   PV (K=16): A = hP^T (3 projected rows + zero pad, b64 loads), B = P regs
//   => C[row=c, col=m]. ZERO LDS ops in the loop: no P staging, no lgkmcnt,
//   LDS shrinks 42 KB -> ~9 KB (merge buffers only) -> thread-cap occupancy.
// ---------------------------------------------------------------------------
__global__ __launch_bounds__(512, 6) void attn_partial_kernel(
    const _Float16* __restrict__ fH, const _Float16* __restrict__ fL,
    const _Float16* __restrict__ gH, const _Float16* __restrict__ gL,
    const _Float16* __restrict__ hP,
    float* __restrict__ pnum, float* __restrict__ pM, float* __restrict__ pL)
{
    const int gb = blockIdx.x;             // 0 .. NGROUP*KSPLIT-1
    const int g  = gb >> 1;                // query group
    const int ks = gb & 1;                 // key-split id
    const int b = g / (NN / 32);
    const int m0 = (g % (NN / 32)) * 32;
    const int tid = threadIdx.x;
    const int w = tid >> 6;                // wave id 0..7
    const int lane = tid & 63;
    const int l16 = lane & 15;
    const int quad = lane >> 4;

    __shared__ float accbuf[NSPLIT][CC][33];  // [w][c][m]
    __shared__ float mbuf[NSPLIT][32];        // [w][m]
    __shared__ float lbuf[NSPLIT][4][32];     // [w][quad][m] quad-partial sums

    // Q B-fragments for both tiles (hi + lo, log2e-scaled)
    const _Float16* gHb = gH + ((size_t)b * NN + m0 + l16) * DD + quad * 8;
    const _Float16* gLb = gL + ((size_t)b * NN + m0 + l16) * DD + quad * 8;
    half8 qh0 = *(const half8*)(gHb);
    half8 ql0 = *(const half8*)(gLb);
    half8 qh1 = *(const half8*)(gHb + (size_t)16 * DD);
    half8 ql1 = *(const half8*)(gLb + (size_t)16 * DD);

    float4v acc0 = {0,0,0,0};              // tile0: C[row=c=quad*4+r][m=l16]
    float4v acc1 = {0,0,0,0};              // tile1 (quad0 rows 0..2 useful)
    float mrun0 = -1e30f, lrun0 = 0.f;     // per-lane col stats (log2 dom.)
    float mrun1 = -1e30f, lrun1 = 0.f;     // lrun = quad-partial sum

    const int nbase = ks * (NN / KSPLIT) + w * KEYS_PER_WAVE;
    // hP^T K16 A-frag pointer: row = min(l16,3), k-offset quad*4
    const int vrow = (l16 < 3) ? l16 : 3;
    const _Float16* vp = hP + ((size_t)(b * 4 + vrow)) * NN + nbase + quad * 4;
    const _Float16* khp = fH + ((size_t)b * NN + nbase + l16) * DD + quad * 8;
    const _Float16* klp = fL + ((size_t)b * NN + nbase + l16) * DD + quad * 8;

    for (int c = 0; c < CHUNKS; ++c) {
        // ---- K fragments (8 x b128) and projected-V K16 A-frags (4 x b64)
        half8 ka[4], kl[4];
        half4v vA[4];
#pragma unroll
        for (int blk = 0; blk < 4; blk++) {
            ka[blk] = *(const half8*)(khp + (size_t)(c * 64 + blk * 16) * DD);
            kl[blk] = *(const half8*)(klp + (size_t)(c * 64 + blk * 16) * DD);
            vA[blk] = *(const half4v*)(vp + c * 64 + blk * 16);
        }

        // ================= tile 0: scores + softmax + PV ==================
        {
            float4v s[4];
#pragma unroll
            for (int blk = 0; blk < 4; blk++) {
                float4v z = {0,0,0,0};
                float4v t = MFMA_K32(ka[blk], ql0, z);
                t = MFMA_K32(kl[blk], qh0, t);
                s[blk] = MFMA_K32(ka[blk], qh0, t);
            }
            float mb0 = fmaxf(fmaxf(s[0][0], s[0][1]), fmaxf(s[0][2], s[0][3]));
            float mb1 = fmaxf(fmaxf(s[1][0], s[1][1]), fmaxf(s[1][2], s[1][3]));
            float mb2 = fmaxf(fmaxf(s[2][0], s[2][1]), fmaxf(s[2][2], s[2][3]));
            float mb3 = fmaxf(fmaxf(s[3][0], s[3][1]), fmaxf(s[3][2], s[3][3]));
            float mx = fmaxf(fmaxf(mb0, mb1), fmaxf(mb2, mb3));
            mx = fmaxf(mx, __shfl_xor(mx, 16, 64));
            mx = fmaxf(mx, __shfl_xor(mx, 32, 64));
            float mnew = fmaxf(mrun0, mx);
            float rsum = 0.f;
            half4v pv[4];
#pragma unroll
            for (int blk = 0; blk < 4; blk++) {
                float p0 = __builtin_amdgcn_exp2f(s[blk][0] - mnew);
                float p1 = __builtin_amdgcn_exp2f(s[blk][1] - mnew);
                float p2 = __builtin_amdgcn_exp2f(s[blk][2] - mnew);
                float p3 = __builtin_amdgcn_exp2f(s[blk][3] - mnew);
                union { fp16x2 h2[2]; half4v h4; } u;
                u.h2[0] = __builtin_amdgcn_cvt_pkrtz(p0, p1);
                u.h2[1] = __builtin_amdgcn_cvt_pkrtz(p2, p3);
                pv[blk] = u.h4;
                rsum += (p0 + p1) + (p2 + p3);
            }
            if (__any(mnew > mrun0)) {
                float alpha = __builtin_amdgcn_exp2f(mrun0 - mnew);
#pragma unroll
                for (int r = 0; r < 4; r++) acc0[r] *= alpha;
                lrun0 = lrun0 * alpha + rsum;
                mrun0 = mnew;
            } else {
                lrun0 += rsum;
            }
            // PV: A = hP^T (regs), B = P (score regs) — no LDS round-trip
#pragma unroll
            for (int blk = 0; blk < 4; blk++)
                acc0 = MFMA_K16(vA[blk], pv[blk], acc0);
        }
        // ================= tile 1: scores + softmax + PV ==================
        {
            float4v s[4];
#pragma unroll
            for (int blk = 0; blk < 4; blk++) {
                float4v z = {0,0,0,0};
                float4v t = MFMA_K32(ka[blk], ql1, z);
                t = MFMA_K32(kl[blk], qh1, t);
                s[blk] = MFMA_K32(ka[blk], qh1, t);
            }
            float mb0 = fmaxf(fmaxf(s[0][0], s[0][1]), fmaxf(s[0][2], s[0][3]));
            float mb1 = fmaxf(fmaxf(s[1][0], s[1][1]), fmaxf(s[1][2], s[1][3]));
            float mb2 = fmaxf(fmaxf(s[2][0], s[2][1]), fmaxf(s[2][2], s[2][3]));
            float mb3 = fmaxf(fmaxf(s[3][0], s[3][1]), fmaxf(s[3][2], s[3][3]));
            float mx = fmaxf(fmaxf(mb0, mb1), fmaxf(mb2, mb3));
            mx = fmaxf(mx, __shfl_xor(mx, 16, 64));
            mx = fmaxf(mx, __shfl_xor(mx, 32, 64));
            float mnew = fmaxf(mrun1, mx);
            float rsum = 0.f;
            half4v pv[4];
#pragma unroll
            for (int blk = 0; blk < 4; blk++) {
                float p0 = __builtin_amdgcn_exp2f(s[blk][0] - mnew);
                float p1 = __builtin_amdgcn_exp2f(s[blk][1] - mnew);
                float p2 = __builtin_amdgcn_exp2f(s[blk][2] - mnew);
                float p3 = __builtin_amdgcn_exp2f(s[blk][3] - mnew);
                union { fp16x2 h2[2]; half4v h4; } u;
                u.h2[0] = __builtin_amdgcn_cvt_pkrtz(p0, p1);
                u.h2[1] = __builtin_amdgcn_cvt_pkrtz(p2, p3);
                pv[blk] = u.h4;
                rsum += (p0 + p1) + (p2 + p3);
            }
            if (__any(mnew > mrun1)) {
                float alpha = __builtin_amdgcn_exp2f(mrun1 - mnew);
#pragma unroll
                for (int r = 0; r < 4; r++) acc1[r] *= alpha;
                lrun1 = lrun1 * alpha + rsum;
                mrun1 = mnew;
            } else {
                lrun1 += rsum;
            }
#pragma unroll
            for (int blk = 0; blk < 4; blk++)
                acc1 = MFMA_K16(vA[blk], pv[blk], acc1);
        }
    }

    // ---- write per-wave partials (fp32) for the in-block merge
    mbuf[w][l16]            = mrun0;   // quad-redundant, same value
    mbuf[w][l16 + 16]       = mrun1;
    lbuf[w][quad][l16]      = lrun0;   // quad-partial sums
    lbuf[w][quad][l16 + 16] = lrun1;
    if (quad == 0) {
#pragma unroll
        for (int r = 0; r < 3; r++) {
            accbuf[w][r][l16]      = acc0[r];   // C rows c=0..2 live in quad 0
            accbuf[w][r][l16 + 16] = acc1[r];
        }
    }
    __syncthreads();

    // ---- merge 8 waves x 4 quads -> un-normalized block partial -> global
    if (tid < CC * 32) {
        int c = tid >> 5, m = tid & 31;
        float M = mbuf[0][m];
#pragma unroll
        for (int s2 = 1; s2 < NSPLIT; s2++) M = fmaxf(M, mbuf[s2][m]);
        float L = 0.f, num = 0.f;
#pragma unroll
        for (int s2 = 0; s2 < NSPLIT; s2++) {
            float e2 = __builtin_amdgcn_exp2f(mbuf[s2][m] - M);
            float lsum = (lbuf[s2][0][m] + lbuf[s2][1][m]) + (lbuf[s2][2][m] + lbuf[s2][3][m]);
            L += lsum * e2;
            num += accbuf[s2][c][m] * e2;
        }
        pnum[(size_t)gb * (CC * 32) + tid] = num;
        if (c == 0) { pM[gb * 32 + m] = M; pL[gb * 32 + m] = L; }
    }
}

// ---------------------------------------------------------------------------
// Final merge: 2-way log-sum-exp combine of the block partials, + ob, clamp.
// ---------------------------------------------------------------------------
__global__ __launch_bounds__(128) void merge_kernel(
    const float* __restrict__ pnum, const float* __restrict__ pM,
    const float* __restrict__ pL, const float* __restrict__ ob,
    float* __restrict__ out)
{
    const int g = blockIdx.x;              // 0 .. NGROUP-1
    const int b = g / (NN / 32);
    const int m0 = (g % (NN / 32)) * 32;
    const int tid = threadIdx.x;
    const int gb0 = g * 2, gb1 = g * 2 + 1;

    if (tid < CC * 32) {
        int c = tid >> 5, m = tid & 31;
        float M0 = pM[gb0 * 32 + m], M1 = pM[gb1 * 32 + m];
        float M = fmaxf(M0, M1);
        float e0 = __builtin_amdgcn_exp2f(M0 - M);
        float e1 = __builtin_amdgcn_exp2f(M1 - M);
        float L = pL[gb0 * 32 + m] * e0 + pL[gb1 * 32 + m] * e1;
        float num = pnum[(size_t)gb0 * (CC * 32) + tid] * e0 +
                    pnum[(size_t)gb1 * (CC * 32) + tid] * e1;
        float o = num / L + ob[c];
        o = fminf(1.f, fmaxf(-1.f, o));
        out[((size_t)b * CC + c) * NN + m0 + m] = o;
    }
}

extern "C" void kernel_launch(void* const* d_in, const int* in_sizes, int n_in,
                              void* d_out, int out_size, void* d_ws, size_t ws_size,
                              hipStream_t stream) {
    const float* img = (const float*)d_in[0];
    const float* kw  = (const float*)d_in[1];
    const float* kb  = (const float*)d_in[2];
    const float* qw  = (const float*)d_in[3];
    const float* qb  = (const float*)d_in[4];
    const float* vw  = (const float*)d_in[5];
    const float* vb  = (const float*)d_in[6];
    const float* ow  = (const float*)d_in[7];
    const float* ob  = (const float*)d_in[8];
    float* out = (float*)d_out;

    // Workspace: fH,fL,gH,gL fp16 (4.7 MB) + hP fp16 [B][4][N] (148 KB)
    // + pnum (442 KB) + pM/pL (147 KB each) ~= 5.6 MB
    const size_t sz = (size_t)BB * NN * DD;
    _Float16* fH = (_Float16*)d_ws;
    _Float16* fL = fH + sz;
    _Float16* gH = fL + sz;
    _Float16* gL = gH + sz;
    _Float16* hP = gL + sz;
    float* pnum = (float*)(hP + (size_t)BB * 4 * NN);
    float* pM   = pnum + (size_t)NGROUP * KSPLIT * CC * 32;
    float* pL   = pM + (size_t)NGROUP * KSPLIT * 32;

    prep_kernel<<<324, 256, 0, stream>>>(img, kw, kb, qw, qb, vw, vb, ow,
                                         fH, fL, gH, gL, hP);
    attn_partial_kernel<<<NGROUP * KSPLIT, 512, 0, stream>>>(
        fH, fL, gH, gL, hP, pnum, pM, pL);
    merge_kernel<<<NGROUP, 128, 0, stream>>>(pnum, pM, pL, ob, out);
}

// Round 18
// 140.871 us; speedup vs baseline: 1.4170x; 1.4170x over previous
//
#include <hip/hip_runtime.h>
#include <hip/hip_fp16.h>

// Problem constants (B,C,H,W = 2,3,96,96; D=32)
#define BB 2
#define CC 3
#define NN 9216   // 96*96
#define DD 32
#define NSPLIT 8                      // waves per block
#define KSPLIT 2                      // blocks per 32-query group
#define KEYS_PER_WAVE (NN / (KSPLIT * NSPLIT))  // 576
#define CHUNKS (KEYS_PER_WAVE / 64)   // 9
#define NGROUP (BB * NN / 32)         // 576 query groups
#define L2E 1.44269504f

typedef _Float16 half8 __attribute__((ext_vector_type(8)));
typedef _Float16 half4v __attribute__((ext_vector_type(4)));
typedef __fp16 fp16x2 __attribute__((ext_vector_type(2)));
typedef float float4v __attribute__((ext_vector_type(4)));

#define MFMA_K32(a, b, c) __builtin_amdgcn_mfma_f32_16x16x32_f16((a), (b), (c), 0, 0, 0)
#define MFMA_K16(a, b, c) __builtin_amdgcn_mfma_f32_16x16x16f16((a), (b), (c), 0, 0, 0)

// ---------------------------------------------------------------------------
// Fused prep (R15-proven). Blocks [0,288): QK — hi/lo fp16 split, Q
// pre-scaled by log2(e). Blocks [288,324): PROJECTED V — hP[c][n] =
// (ow.vw).x + ow.vb for c in 0..2 plus a zero row 3 (3x3 cw computed
// in-block; exact fold of the output projection into V).
// ---------------------------------------------------------------------------
__global__ __launch_bounds__(256) void prep_kernel(
    const float* __restrict__ img,
    const float* __restrict__ kw, const float* __restrict__ kb,
    const float* __restrict__ qw, const float* __restrict__ qb,
    const float* __restrict__ vw, const float* __restrict__ vb,
    const float* __restrict__ ow,
    _Float16* __restrict__ fH, _Float16* __restrict__ fL,
    _Float16* __restrict__ gH, _Float16* __restrict__ gL,
    _Float16* __restrict__ hP)
{
    __shared__ float cwb[12];
    int bid = blockIdx.x;
    if (bid < 288) {
        int id = bid * 256 + threadIdx.x;          // [0, BB*NN*4)
        int part = id & 3;
        int n = (id >> 2) % NN;
        int b = (id >> 2) / NN;
        const float* xb = img + (size_t)b * CC * NN + n;
        float x0 = xb[0], x1 = xb[NN], x2 = xb[2 * NN];
        half8 fh, fl, gh, gl;
#pragma unroll
        for (int j = 0; j < 8; j++) {
            int d = part * 8 + j;
            float fv = kw[d * 3 + 0] * x0 + kw[d * 3 + 1] * x1 + kw[d * 3 + 2] * x2 + kb[d];
            float gv = (qw[d * 3 + 0] * x0 + qw[d * 3 + 1] * x1 + qw[d * 3 + 2] * x2 + qb[d]) * L2E;
            _Float16 fhi = (_Float16)fv;
            _Float16 ghi = (_Float16)gv;
            fh[j] = fhi; fl[j] = (_Float16)(fv - (float)fhi);
            gh[j] = ghi; gl[j] = (_Float16)(gv - (float)ghi);
        }
        size_t off = ((size_t)b * NN + n) * DD + part * 8;
        *(half8*)(fH + off) = fh;
        *(half8*)(fL + off) = fl;
        *(half8*)(gH + off) = gh;
        *(half8*)(gL + off) = gl;
    } else {
        int t = threadIdx.x;
        if (t < 9) {
            int c = t / 3, k = t % 3;
            float s = 0.f;
#pragma unroll
            for (int d = 0; d < DD; d++) s += ow[c * DD + d] * vw[d * 3 + k];
            cwb[t] = s;
        } else if (t < 12) {
            int c = t - 9;
            float s = 0.f;
#pragma unroll
            for (int d = 0; d < DD; d++) s += ow[c * DD + d] * vb[d];
            cwb[9 + c] = s;
        }
        __syncthreads();
        const int N8 = NN / 8;
        int id = (bid - 288) * 256 + t;            // [0, BB*4*N8) = 9216
        int n8 = id % N8;
        int row = (id / N8) & 3;
        int b = id / (N8 * 4);
        half8 hv = {0, 0, 0, 0, 0, 0, 0, 0};
        if (row < 3) {
            const float* xb = img + (size_t)b * CC * NN + n8 * 8;
            float w0 = cwb[row * 3 + 0], w1 = cwb[row * 3 + 1],
                  w2 = cwb[row * 3 + 2], bv = cwb[9 + row];
#pragma unroll
            for (int j = 0; j < 8; j++)
                hv[j] = (_Float16)(w0 * xb[j] + w1 * xb[NN + j] + w2 * xb[2 * NN + j] + bv);
        }
        *(half8*)(hP + ((size_t)(b * 4 + row)) * NN + n8 * 8) = hv;
    }
}

// ---------------------------------------------------------------------------
// Flash attention PARTIAL, cross-block split-K x2, FULLY REGISTER inner loop:
//   S (K=32): A = K, B = Q => C[row=n=quad*4+r, col=m=l16]  (R12-proven).
//   P = exp2(s - mnew) packed to fp16 pairs — the score-register C-layout IS
//   the K=16 MFMA B-operand layout (k=quad*4+j, col=l16; HW-verified in R7).
//   PV (K=16): A = hP^T (3 projected rows + zero pad, b64 loads), B = P regs
//   => C[row=c, col=m]. ZERO LDS ops in the loop.
//   launch_bounds(512,4): 128-VGPR cap for the ~104-reg live set — R16's
//   (512,6) cap of ~85 caused 182 MB/dispatch scratch spill.
// ---------------------------------------------------------------------------
__global__ __launch_bounds__(512, 4) void attn_partial_kernel(
    const _Float16* __restrict__ fH, const _Float16* __restrict__ fL,
    const _Float16* __restrict__ gH, const _Float16* __restrict__ gL,
    const _Float16* __restrict__ hP,
    float* __restrict__ pnum, float* __restrict__ pM, float* __restrict__ pL)
{
    const int gb = blockIdx.x;             // 0 .. NGROUP*KSPLIT-1
    const int g  = gb >> 1;                // query group
    const int ks = gb & 1;                 // key-split id
    const int b = g / (NN / 32);
    const int m0 = (g % (NN / 32)) * 32;
    const int tid = threadIdx.x;
    const int w = tid >> 6;                // wave id 0..7
    const int lane = tid & 63;
    const int l16 = lane & 15;
    const int quad = lane >> 4;

    __shared__ float accbuf[NSPLIT][CC][33];  // [w][c][m]
    __shared__ float mbuf[NSPLIT][32];        // [w][m]
    __shared__ float lbuf[NSPLIT][4][32];     // [w][quad][m] quad-partial sums

    // Q B-fragments for both tiles (hi + lo, log2e-scaled)
    const _Float16* gHb = gH + ((size_t)b * NN + m0 + l16) * DD + quad * 8;
    const _Float16* gLb = gL + ((size_t)b * NN + m0 + l16) * DD + quad * 8;
    half8 qh0 = *(const half8*)(gHb);
    half8 ql0 = *(const half8*)(gLb);
    half8 qh1 = *(const half8*)(gHb + (size_t)16 * DD);
    half8 ql1 = *(const half8*)(gLb + (size_t)16 * DD);

    float4v acc0 = {0,0,0,0};              // tile0: C[row=c=quad*4+r][m=l16]
    float4v acc1 = {0,0,0,0};              // tile1 (quad0 rows 0..2 useful)
    float mrun0 = -1e30f, lrun0 = 0.f;     // per-lane col stats (log2 dom.)
    float mrun1 = -1e30f, lrun1 = 0.f;     // lrun = quad-partial sum

    const int nbase = ks * (NN / KSPLIT) + w * KEYS_PER_WAVE;
    // hP^T K16 A-frag pointer: row = min(l16,3), k-offset quad*4
    const int vrow = (l16 < 3) ? l16 : 3;
    const _Float16* vp = hP + ((size_t)(b * 4 + vrow)) * NN + nbase + quad * 4;
    const _Float16* khp = fH + ((size_t)b * NN + nbase + l16) * DD + quad * 8;
    const _Float16* klp = fL + ((size_t)b * NN + nbase + l16) * DD + quad * 8;

    for (int c = 0; c < CHUNKS; ++c) {
        // ---- K fragments (8 x b128) and projected-V K16 A-frags (4 x b64)
        half8 ka[4], kl[4];
        half4v vA[4];
#pragma unroll
        for (int blk = 0; blk < 4; blk++) {
            ka[blk] = *(const half8*)(khp + (size_t)(c * 64 + blk * 16) * DD);
            kl[blk] = *(const half8*)(klp + (size_t)(c * 64 + blk * 16) * DD);
            vA[blk] = *(const half4v*)(vp + c * 64 + blk * 16);
        }

        // ================= tile 0: scores + softmax + PV ==================
        {
            float4v s[4];
#pragma unroll
            for (int blk = 0; blk < 4; blk++) {
                float4v z = {0,0,0,0};
                float4v t = MFMA_K32(ka[blk], ql0, z);
                t = MFMA_K32(kl[blk], qh0, t);
                s[blk] = MFMA_K32(ka[blk], qh0, t);
            }
            float mb0 = fmaxf(fmaxf(s[0][0], s[0][1]), fmaxf(s[0][2], s[0][3]));
            float mb1 = fmaxf(fmaxf(s[1][0], s[1][1]), fmaxf(s[1][2], s[1][3]));
            float mb2 = fmaxf(fmaxf(s[2][0], s[2][1]), fmaxf(s[2][2], s[2][3]));
            float mb3 = fmaxf(fmaxf(s[3][0], s[3][1]), fmaxf(s[3][2], s[3][3]));
            float mx = fmaxf(fmaxf(mb0, mb1), fmaxf(mb2, mb3));
            mx = fmaxf(mx, __shfl_xor(mx, 16, 64));
            mx = fmaxf(mx, __shfl_xor(mx, 32, 64));
            float mnew = fmaxf(mrun0, mx);
            float rsum = 0.f;
            half4v pv[4];
#pragma unroll
            for (int blk = 0; blk < 4; blk++) {
                float p0 = __builtin_amdgcn_exp2f(s[blk][0] - mnew);
                float p1 = __builtin_amdgcn_exp2f(s[blk][1] - mnew);
                float p2 = __builtin_amdgcn_exp2f(s[blk][2] - mnew);
                float p3 = __builtin_amdgcn_exp2f(s[blk][3] - mnew);
                union { fp16x2 h2[2]; half4v h4; } u;
                u.h2[0] = __builtin_amdgcn_cvt_pkrtz(p0, p1);
                u.h2[1] = __builtin_amdgcn_cvt_pkrtz(p2, p3);
                pv[blk] = u.h4;
                rsum += (p0 + p1) + (p2 + p3);
            }
            if (__any(mnew > mrun0)) {
                float alpha = __builtin_amdgcn_exp2f(mrun0 - mnew);
#pragma unroll
                for (int r = 0; r < 4; r++) acc0[r] *= alpha;
                lrun0 = lrun0 * alpha + rsum;
                mrun0 = mnew;
            } else {
                lrun0 += rsum;
            }
            // PV: A = hP^T (regs), B = P (score regs) — no LDS round-trip
#pragma unroll
            for (int blk = 0; blk < 4; blk++)
                acc0 = MFMA_K16(vA[blk], pv[blk], acc0);
        }
        // ================= tile 1: scores + softmax + PV ==================
        {
            float4v s[4];
#pragma unroll
            for (int blk = 0; blk < 4; blk++) {
                float4v z = {0,0,0,0};
                float4v t = MFMA_K32(ka[blk], ql1, z);
                t = MFMA_K32(kl[blk], qh1, t);
                s[blk] = MFMA_K32(ka[blk], qh1, t);
            }
            float mb0 = fmaxf(fmaxf(s[0][0], s[0][1]), fmaxf(s[0][2], s[0][3]));
            float mb1 = fmaxf(fmaxf(s[1][0], s[1][1]), fmaxf(s[1][2], s[1][3]));
            float mb2 = fmaxf(fmaxf(s[2][0], s[2][1]), fmaxf(s[2][2], s[2][3]));
            float mb3 = fmaxf(fmaxf(s[3][0], s[3][1]), fmaxf(s[3][2], s[3][3]));
            float mx = fmaxf(fmaxf(mb0, mb1), fmaxf(mb2, mb3));
            mx = fmaxf(mx, __shfl_xor(mx, 16, 64));
            mx = fmaxf(mx, __shfl_xor(mx, 32, 64));
            float mnew = fmaxf(mrun1, mx);
            float rsum = 0.f;
            half4v pv[4];
#pragma unroll
            for (int blk = 0; blk < 4; blk++) {
                float p0 = __builtin_amdgcn_exp2f(s[blk][0] - mnew);
                float p1 = __builtin_amdgcn_exp2f(s[blk][1] - mnew);
                float p2 = __builtin_amdgcn_exp2f(s[blk][2] - mnew);
                float p3 = __builtin_amdgcn_exp2f(s[blk][3] - mnew);
                union { fp16x2 h2[2]; half4v h4; } u;
                u.h2[0] = __builtin_amdgcn_cvt_pkrtz(p0, p1);
                u.h2[1] = __builtin_amdgcn_cvt_pkrtz(p2, p3);
                pv[blk] = u.h4;
                rsum += (p0 + p1) + (p2 + p3);
            }
            if (__any(mnew > mrun1)) {
                float alpha = __builtin_amdgcn_exp2f(mrun1 - mnew);
#pragma unroll
                for (int r = 0; r < 4; r++) acc1[r] *= alpha;
                lrun1 = lrun1 * alpha + rsum;
                mrun1 = mnew;
            } else {
                lrun1 += rsum;
            }
#pragma unroll
            for (int blk = 0; blk < 4; blk++)
                acc1 = MFMA_K16(vA[blk], pv[blk], acc1);
        }
    }

    // ---- write per-wave partials (fp32) for the in-block merge
    mbuf[w][l16]            = mrun0;   // quad-redundant, same value
    mbuf[w][l16 + 16]       = mrun1;
    lbuf[w][quad][l16]      = lrun0;   // quad-partial sums
    lbuf[w][quad][l16 + 16] = lrun1;
    if (quad == 0) {
#pragma unroll
        for (int r = 0; r < 3; r++) {
            accbuf[w][r][l16]      = acc0[r];   // C rows c=0..2 live in quad 0
            accbuf[w][r][l16 + 16] = acc1[r];
        }
    }
    __syncthreads();

    // ---- merge 8 waves x 4 quads -> un-normalized block partial -> global
    if (tid < CC * 32) {
        int c = tid >> 5, m = tid & 31;
        float M = mbuf[0][m];
#pragma unroll
        for (int s2 = 1; s2 < NSPLIT; s2++) M = fmaxf(M, mbuf[s2][m]);
        float L = 0.f, num = 0.f;
#pragma unroll
        for (int s2 = 0; s2 < NSPLIT; s2++) {
            float e2 = __builtin_amdgcn_exp2f(mbuf[s2][m] - M);
            float lsum = (lbuf[s2][0][m] + lbuf[s2][1][m]) + (lbuf[s2][2][m] + lbuf[s2][3][m]);
            L += lsum * e2;
            num += accbuf[s2][c][m] * e2;
        }
        pnum[(size_t)gb * (CC * 32) + tid] = num;
        if (c == 0) { pM[gb * 32 + m] = M; pL[gb * 32 + m] = L; }
    }
}

// ---------------------------------------------------------------------------
// Final merge: 2-way log-sum-exp combine of the block partials, + ob, clamp.
// ---------------------------------------------------------------------------
__global__ __launch_bounds__(128) void merge_kernel(
    const float* __restrict__ pnum, const float* __restrict__ pM,
    const float* __restrict__ pL, const float* __restrict__ ob,
    float* __restrict__ out)
{
    const int g = blockIdx.x;              // 0 .. NGROUP-1
    const int b = g / (NN / 32);
    const int m0 = (g % (NN / 32)) * 32;
    const int tid = threadIdx.x;
    const int gb0 = g * 2, gb1 = g * 2 + 1;

    if (tid < CC * 32) {
        int c = tid >> 5, m = tid & 31;
        float M0 = pM[gb0 * 32 + m], M1 = pM[gb1 * 32 + m];
        float M = fmaxf(M0, M1);
        float e0 = __builtin_amdgcn_exp2f(M0 - M);
        float e1 = __builtin_amdgcn_exp2f(M1 - M);
        float L = pL[gb0 * 32 + m] * e0 + pL[gb1 * 32 + m] * e1;
        float num = pnum[(size_t)gb0 * (CC * 32) + tid] * e0 +
                    pnum[(size_t)gb1 * (CC * 32) + tid] * e1;
        float o = num / L + ob[c];
        o = fminf(1.f, fmaxf(-1.f, o));
        out[((size_t)b * CC + c) * NN + m0 + m] = o;
    }
}

extern "C" void kernel_launch(void* const* d_in, const int* in_sizes, int n_in,
                              void* d_out, int out_size, void* d_ws, size_t ws_size,
                              hipStream_t stream) {
    const float* img = (const float*)d_in[0];
    const float* kw  = (const float*)d_in[1];
    const float* kb  = (const float*)d_in[2];
    const float* qw  = (const float*)d_in[3];
    const float* qb  = (const float*)d_in[4];
    const float* vw  = (const float*)d_in[5];
    const float* vb  = (const float*)d_in[6];
    const float* ow  = (const float*)d_in[7];
    const float* ob  = (const float*)d_in[8];
    float* out = (float*)d_out;

    // Workspace: fH,fL,gH,gL fp16 (4.7 MB) + hP fp16 [B][4][N] (148 KB)
    // + pnum (442 KB) + pM/pL (147 KB each) ~= 5.6 MB
    const size_t sz = (size_t)BB * NN * DD;
    _Float16* fH = (_Float16*)d_ws;
    _Float16* fL = fH + sz;
    _Float16* gH = fL + sz;
    _Float16* gL = gH + sz;
    _Float16* hP = gL + sz;
    float* pnum = (float*)(hP + (size_t)BB * 4 * NN);
    float* pM   = pnum + (size_t)NGROUP * KSPLIT * CC * 32;
    float* pL   = pM + (size_t)NGROUP * KSPLIT * 32;

    prep_kernel<<<324, 256, 0, stream>>>(img, kw, kb, qw, qb, vw, vb, ow,
                                         fH, fL, gH, gL, hP);
    attn_partial_kernel<<<NGROUP * KSPLIT, 512, 0, stream>>>(
        fH, fL, gH, gL, hP, pnum, pM, pL);
    merge_kernel<<<NGROUP, 128, 0, stream>>>(pnum, pM, pL, ob, out);
}